// Round 8
// baseline (647.652 us; speedup 1.0000x reference)
//
#include <hip/hip_runtime.h>
#include <hip/hip_bf16.h>

// ---------------------------------------------------------------------------
// DenseCorr2d_full — round 8: round 7 with the tmb_prep OOB fixed.
//
// ROOT CAUSE of rounds 6-7 aborts: tmb_prep grid was 11520 blocks =
// 2,949,120 threads, but tmb has 8*16*143*144 = 2,635,776 elements; unguarded
// excess threads computed bc up to 143 (>127) and read tm out of bounds.
// Fix: grid 10,296 (exact) + explicit guard. Everything else identical.
//
// corr_g2: global-direct MFMA corr. Per (kc,c2): two ALIGNED dwordx4 loads
//   give a 32-B window w[0..7]; the 8 x-sub-shift B-octets are register
//   selects (even s) or 16-bit funnel shifts (odd s). No LDS, no barriers.
// merge_mfma: round-4 version VERBATIM (measured 89.5 us, passed twice).
// ws: corrb bf16 NHWC [8][128][128][256]  67,108,864 B
//     Wb   bf16 [9][64][256]                 294,912 B
//     tmb  bf16 [8][16][143][144]          5,271,552 B   total 72,675,328 B
// ---------------------------------------------------------------------------

typedef __attribute__((ext_vector_type(4))) float  f32x4;
typedef __attribute__((ext_vector_type(8))) short  bf16x8;

__device__ inline unsigned int pack_bf16x2(float a, float b) {
    unsigned int ua = __builtin_bit_cast(unsigned int, a);
    unsigned int ub = __builtin_bit_cast(unsigned int, b);
    ua = (ua + 0x7fffu + ((ua >> 16) & 1u)) >> 16;   // RNE
    ub = (ub + 0x7fffu + ((ub >> 16) & 1u)) >> 16;
    return ua | (ub << 16);
}
__device__ inline unsigned short cvt1(float f) {
    unsigned int u = __builtin_bit_cast(unsigned int, f);
    return (unsigned short)((u + 0x7fffu + ((u >> 16) & 1u)) >> 16);
}

// ---------------- tm pre-pad (single copy): tmb[b][cm][r 143][c 144] --------
__global__ __launch_bounds__(256) void tmb_prep(
    const float* __restrict__ tm, unsigned short* __restrict__ tmb)
{
    int idx = (int)blockIdx.x * 256 + (int)threadIdx.x;
    if (idx >= 8 * 16 * 143 * 144) return;            // 2,635,776
    int c   = idx % 144;
    int rem = idx / 144;
    int r   = rem % 143;
    int bc  = rem / 143;                              // b*16+cm, 0..127
    int gy = r > 127 ? 127 : r;
    int gx = c > 127 ? 127 : c;
    tmb[idx] = cvt1(tm[(((size_t)bc) << 14) + (gy << 7) + gx]);
}

// ---------------- Stage 1: correlation, aligned global B-frags --------------
// Wave w of block -> y row (blockIdx.x*4 + w), one (b, cm-pair).
// MFMA n = 16 x positions strided 8 (x = 8n+s). k = i*16+j; octet(kc,quad):
// i = 2kc+qh, j = 8jq+e. Octets for all 8 s come from one 32-B window.
__global__ __launch_bounds__(256) void corr_g2(
    const float* __restrict__ tp, const unsigned short* __restrict__ tmb,
    unsigned short* __restrict__ corrb)
{
    const int t    = threadIdx.x;
    const int wave = t >> 6, lane = t & 63;
    const int n    = lane & 15, quad = lane >> 4;
    const int qh   = quad >> 1, jq = quad & 1;

    const int y    = ((int)blockIdx.x << 2) + wave;   // 0..127
    const int pair = (int)blockIdx.y & 7;
    const int b    = (int)blockIdx.y >> 3;

    // A-frags: tp[b][ct=n][i=2kc+qh][8jq .. +7], fp32 -> bf16, register-cached
    bf16x8 bq[8];
    {
        const float* tpb = tp + (((size_t)(b * 16 + n)) << 8);
#pragma unroll
        for (int kc = 0; kc < 8; ++kc) {
            const float4* q = (const float4*)(tpb + (((2 * kc + qh) << 4) + (jq << 3)));
            float4 a = q[0], c4 = q[1];
            union { uint4 u; bf16x8 h; } cv;
            cv.u.x = pack_bf16x2(a.x, a.y);
            cv.u.y = pack_bf16x2(a.z, a.w);
            cv.u.z = pack_bf16x2(c4.x, c4.y);
            cv.u.w = pack_bf16x2(c4.z, c4.w);
            bq[kc] = cv.h;
        }
    }

    const size_t PLANE = 20592;                       // 143*144 shorts
    const unsigned short* base0 = tmb
        + (size_t)(b * 16 + pair * 2) * PLANE + (n << 3) + (jq << 3);

    f32x4 acc[2][8];                                  // [cm2][s]
#pragma unroll
    for (int c2 = 0; c2 < 2; ++c2)
#pragma unroll
        for (int s = 0; s < 8; ++s) acc[c2][s] = (f32x4){0.f, 0.f, 0.f, 0.f};

    unsigned int w[8];
    {   // window for u=0 (kc=0, c2=0): row y+qh
        const uint4* p = (const uint4*)(base0 + (size_t)(y + qh) * 144);
        uint4 lo = p[0], hi = p[1];
        w[0] = lo.x; w[1] = lo.y; w[2] = lo.z; w[3] = lo.w;
        w[4] = hi.x; w[5] = hi.y; w[6] = hi.z; w[7] = hi.w;
    }

#pragma unroll 1
    for (int u = 0; u < 16; ++u) {                    // u = kc*2 + c2
        const int kc = u >> 1, c2 = u & 1;
        // Prefetch next window; un clamped -> always valid, wn always init.
        const int un = u < 15 ? u + 1 : 15;
        unsigned int wn[8];
        {
            const uint4* p = (const uint4*)(base0
                + (size_t)(un & 1) * PLANE
                + (size_t)(y + ((un >> 1) << 1) + qh) * 144);
            uint4 lo = p[0], hi = p[1];
            wn[0] = lo.x; wn[1] = lo.y; wn[2] = lo.z; wn[3] = lo.w;
            wn[4] = hi.x; wn[5] = hi.y; wn[6] = hi.z; wn[7] = hi.w;
        }
#pragma unroll
        for (int s = 0; s < 8; ++s) {
            union { uint4 u4; bf16x8 h; } f;
            const int q = s >> 1;
            if ((s & 1) == 0) {                       // even shift: reg select
                f.u4.x = w[q]; f.u4.y = w[q + 1];
                f.u4.z = w[q + 2]; f.u4.w = w[q + 3];
            } else {                                  // odd: 16-bit funnel
                f.u4.x = (w[q] >> 16)     | (w[q + 1] << 16);
                f.u4.y = (w[q + 1] >> 16) | (w[q + 2] << 16);
                f.u4.z = (w[q + 2] >> 16) | (w[q + 3] << 16);
                f.u4.w = (w[q + 3] >> 16) | (w[q + 4] << 16);
            }
            acc[c2][s] = __builtin_amdgcn_mfma_f32_16x16x32_bf16(
                bq[kc], f.h, acc[c2][s], 0, 0, 0);
        }
#pragma unroll
        for (int i = 0; i < 8; ++i) w[i] = wn[i];
    }

    // Epilogue: D[row=quad*4+r = ct][col=n]; x = 8n+s
    const size_t posb = ((size_t)(b * 16384 + (y << 7)) << 8) + (pair << 5);
#pragma unroll
    for (int s = 0; s < 8; ++s) {
        const int x = (n << 3) + s;
#pragma unroll
        for (int c2 = 0; c2 < 2; ++c2) {
            uint2 v;
            v.x = pack_bf16x2(acc[c2][s][0], acc[c2][s][1]);
            v.y = pack_bf16x2(acc[c2][s][2], acc[c2][s][3]);
            *(uint2*)(corrb + posb + ((size_t)x << 8) + (c2 << 4) + (quad << 2)) = v;
        }
    }
}

// ---------------- W transform (round-4): Wb[kk][co][256] bf16 ---------------
__global__ __launch_bounds__(256) void wt_kernel(
    const float* __restrict__ W, unsigned short* __restrict__ Wb)
{
    int idx = (int)blockIdx.x * 256 + (int)threadIdx.x;   // < 9*64*256 exact
    int c  = idx & 255;
    int rem = idx >> 8;
    int co = rem % 64;
    int kk = rem / 64;
    Wb[idx] = cvt1(W[(size_t)co * 2304 + (size_t)c * 9 + kk]);
}

// ---------------- Stage 2: round-4 merge_mfma VERBATIM (known good) ---------
__global__ __launch_bounds__(256) void merge_mfma(
    const unsigned short* __restrict__ corrb, const unsigned short* __restrict__ Wb,
    const float* __restrict__ bias, float* __restrict__ out)
{
    __shared__ __align__(16) unsigned short sm[10 * 34 * 72];  // 48960 B

    const int t    = threadIdx.x;
    const int wave = t >> 6, lane = t & 63;
    const int n    = lane & 15, quad = lane >> 4;
    const int x0   = (int)blockIdx.x << 5;
    const int y0   = (int)blockIdx.y << 3;
    const int b    = (int)blockIdx.z;

    f32x4 acc[4][4];
#pragma unroll
    for (int a = 0; a < 4; ++a)
#pragma unroll
        for (int q = 0; q < 4; ++q) acc[a][q] = (f32x4){0.f, 0.f, 0.f, 0.f};

    const unsigned short* cb = corrb + ((size_t)b << 22);   // b * 16384*256

    uint4 v[11];

#define SLAB_LOAD(C0)                                                        \
    {                                                                        \
        _Pragma("unroll")                                                    \
        for (int k = 0; k < 11; ++k) {                                       \
            int e = t + (k << 8);                                            \
            int ci = e & 7, rem = e >> 3;                                    \
            int cc = rem % 34, r = rem / 34;                                 \
            int gy = y0 - 1 + r, gx = x0 - 1 + cc;                           \
            uint4 vv = {0u, 0u, 0u, 0u};                                     \
            if (e < 2720 && (unsigned)gy < 128u && (unsigned)gx < 128u)      \
                vv = *(const uint4*)(cb + (((size_t)((gy << 7) + gx)) << 8)  \
                                        + (C0) + (ci << 3));                 \
            v[k] = vv;                                                       \
        }                                                                    \
    }
#define SLAB_WRITE()                                                         \
    {                                                                        \
        _Pragma("unroll")                                                    \
        for (int k = 0; k < 11; ++k) {                                       \
            int e = t + (k << 8);                                            \
            int ci = e & 7, rem = e >> 3;                                    \
            int cc = rem % 34, r = rem / 34;                                 \
            if (e < 2720)                                                    \
                *(uint4*)&sm[r * 2448 + cc * 72 + (ci << 3)] = v[k];         \
        }                                                                    \
    }

    SLAB_LOAD(0)
    SLAB_WRITE()
    __syncthreads();

#pragma unroll 1
    for (int c0 = 0; c0 < 256; c0 += 64) {
        if (c0 < 192) SLAB_LOAD(c0 + 64)

        const unsigned short* wpb = Wb + (size_t)n * 256 + c0 + (quad << 3);
        bf16x8 afc[4];
        {
#pragma unroll
            for (int ct = 0; ct < 4; ++ct)
                afc[ct] = *(const bf16x8*)(wpb + (size_t)ct * 4096);
        }
#pragma unroll 1
        for (int idx = 0; idx < 18; ++idx) {
            const int nidx = idx < 17 ? idx + 1 : 17;
            const int nkk = nidx >> 1, nkc = nidx & 1;
            bf16x8 afn[4];
#pragma unroll
            for (int ct = 0; ct < 4; ++ct)
                afn[ct] = *(const bf16x8*)(wpb + (size_t)nkk * 16384
                                               + (nkc << 5) + (size_t)ct * 4096);
            const int kk = idx >> 1, kc = idx & 1;
            const int dy = kk / 3, dx = kk - 3 * dy;
#pragma unroll
            for (int nt = 0; nt < 4; ++nt) {
                const int prow = 2 * wave + (nt >> 1) + dy;
                const int pcol = ((nt & 1) << 4) + n + dx;
                bf16x8 bf = *(const bf16x8*)&sm[prow * 2448 + pcol * 72
                                                + (kc << 5) + (quad << 3)];
#pragma unroll
                for (int ct = 0; ct < 4; ++ct)
                    acc[ct][nt] = __builtin_amdgcn_mfma_f32_16x16x32_bf16(
                        afc[ct], bf, acc[ct][nt], 0, 0, 0);
            }
#pragma unroll
            for (int ct = 0; ct < 4; ++ct) afc[ct] = afn[ct];
        }

        __syncthreads();
        if (c0 < 192) SLAB_WRITE()
        __syncthreads();
    }

#pragma unroll
    for (int ct = 0; ct < 4; ++ct) {
#pragma unroll
        for (int nt = 0; nt < 4; ++nt) {
            const int y   = y0 + 2 * wave + (nt >> 1);
            const int x   = x0 + ((nt & 1) << 4) + n;
            const int co0 = (ct << 4) + (quad << 2);
            float* op = out + (((size_t)((b << 6) + co0) << 7) + y) * 128 + x;
#pragma unroll
            for (int r = 0; r < 4; ++r)
                op[(size_t)r << 14] = acc[ct][nt][r] + bias[co0 + r];
        }
    }
#undef SLAB_LOAD
#undef SLAB_WRITE
}

extern "C" void kernel_launch(void* const* d_in, const int* in_sizes, int n_in,
                              void* d_out, int out_size, void* d_ws, size_t ws_size,
                              hipStream_t stream)
{
    const float* tp   = (const float*)d_in[0];   // template [8,16,16,16]
    const float* tm   = (const float*)d_in[1];   // tomatch  [8,16,128,128]
    const float* Wt   = (const float*)d_in[2];   // W        [64,256,3,3]
    const float* bias = (const float*)d_in[3];   // b        [64]
    float* out = (float*)d_out;                  // [8,64,128,128] fp32

    unsigned short* corrb = (unsigned short*)d_ws;              // 67,108,864 B
    unsigned short* Wb    = corrb + (size_t)8 * 16384 * 256;    //    294,912 B
    unsigned short* tmb   = Wb + (size_t)9 * 64 * 256;          //  5,271,552 B

    tmb_prep<<<dim3(10296), dim3(256), 0, stream>>>(tm, tmb);   // exact grid
    corr_g2<<<dim3(32, 64), dim3(256), 0, stream>>>(tp, tmb, corrb);
    wt_kernel<<<dim3(576), dim3(256), 0, stream>>>(Wt, Wb);
    merge_mfma<<<dim3(4, 16, 8), dim3(256), 0, stream>>>(corrb, Wb, bias, out);
}